// Round 1
// baseline (412.852 us; speedup 1.0000x reference)
//
#include <hip/hip_runtime.h>

#define GRID 32
#define NT 48
#define BLK 256

// Per-edge packed info: bits [0]=base_x, [1]=base_y, [2]=base_z, [4:3]=axis.
// EDGE_BASE[e][axis[e]] == 0 for all 12 edges, so vert = base with comp[axis]=t.
#define EDGE_PACK ( (0ULL<<0) | (9ULL<<5) | (2ULL<<10) | (8ULL<<15) | \
                    (4ULL<<20) | (13ULL<<25) | (6ULL<<30) | (12ULL<<35) | \
                    (16ULL<<40) | (17ULL<<45) | (19ULL<<50) | (18ULL<<55) )

__device__ __forceinline__ float safe_div(float n, float d) {
    float dd = (fabsf(d) > 1e-12f) ? d : 1e-12f;
    return n / dd;
}

__device__ __forceinline__ void get_vert(int i, float t,
                                         float& vx, float& vy, float& vz) {
    unsigned nib = (unsigned)(EDGE_PACK >> (5 * i)) & 31u;
    float bx = (nib & 1u) ? 1.0f : 0.0f;
    float by = (nib & 2u) ? 1.0f : 0.0f;
    float bz = (nib & 4u) ? 1.0f : 0.0f;
    unsigned ax = nib >> 3;
    vx = (ax == 0u) ? t : bx;
    vy = (ax == 1u) ? t : by;
    vz = (ax == 2u) ? t : bz;
}

__device__ float tri_dist_sq(float px, float py, float pz,
                             float ax, float ay, float az,
                             float bx, float by, float bz,
                             float cx, float cy, float cz) {
#pragma clang fp contract(off)
    // Ericson closest-point-on-triangle, replicating the reference's exact
    // select ordering (later `where` wins) and safe_div eps semantics.
    float abx = bx - ax, aby = by - ay, abz = bz - az;
    float acx = cx - ax, acy = cy - ay, acz = cz - az;
    float apx = px - ax, apy = py - ay, apz = pz - az;
    float d1 = abx * apx + aby * apy + abz * apz;
    float d2 = acx * apx + acy * apy + acz * apz;
    float bpx = px - bx, bpy = py - by, bpz = pz - bz;
    float d3 = abx * bpx + aby * bpy + abz * bpz;
    float d4 = acx * bpx + acy * bpy + acz * bpz;
    float cpx = px - cx, cpy = py - cy, cpz = pz - cz;
    float d5 = abx * cpx + aby * cpy + abz * cpz;
    float d6 = acx * cpx + acy * cpy + acz * cpz;
    float vc = d1 * d4 - d3 * d2;
    float vb = d5 * d2 - d1 * d6;
    float va = d3 * d6 - d5 * d4;
    float v_ab = safe_div(d1, d1 - d3);
    float w_ac = safe_div(d2, d2 - d6);
    float w_bc = safe_div(d4 - d3, (d4 - d3) + (d5 - d6));
    float inv  = safe_div(1.0f, va + vb + vc);
    float v_in = vb * inv;
    float w_in = vc * inv;
    float qx = ax + abx * v_in + acx * w_in;
    float qy = ay + aby * v_in + acy * w_in;
    float qz = az + abz * v_in + acz * w_in;
    if ((va <= 0.0f) && (d4 - d3 >= 0.0f) && (d5 - d6 >= 0.0f)) {
        qx = bx + (cx - bx) * w_bc;
        qy = by + (cy - by) * w_bc;
        qz = bz + (cz - bz) * w_bc;
    }
    if ((vb <= 0.0f) && (d2 >= 0.0f) && (d6 <= 0.0f)) {
        qx = ax + acx * w_ac;
        qy = ay + acy * w_ac;
        qz = az + acz * w_ac;
    }
    if ((d6 >= 0.0f) && (d5 <= d6)) { qx = cx; qy = cy; qz = cz; }
    if ((vc <= 0.0f) && (d1 >= 0.0f) && (d3 <= 0.0f)) {
        qx = ax + abx * v_ab;
        qy = ay + aby * v_ab;
        qz = az + abz * v_ab;
    }
    if ((d3 >= 0.0f) && (d4 <= d3)) { qx = bx; qy = by; qz = bz; }
    if ((d1 <= 0.0f) && (d2 <= 0.0f)) { qx = ax; qy = ay; qz = az; }
    float dx = px - qx, dy = py - qy, dz = pz - qz;
    return dx * dx + dy * dy + dz * dz;
}

__global__ __launch_bounds__(BLK) void ptd_kernel(
    const float* __restrict__ offset,     // (3,33,33,33)
    const float* __restrict__ points,     // (N,3)
    const int*   __restrict__ tri_table,  // (48,3,3)
    float*       __restrict__ out,        // (32768,48)
    int n)
{
    // Per-thread 12 edge-t values; stride 13 floats -> bank=(13*lane+e)%32,
    // gcd(13,32)=1 -> only free 2-way aliasing across the wave64.
    __shared__ float t_s[BLK * 13];
    const int tid = threadIdx.x;
    const int idx = blockIdx.x * BLK + tid;
    if (idx >= n) return;

    float px = points[idx * 3 + 0];
    float py = points[idx * 3 + 1];
    float pz = points[idx * 3 + 2];
    int cx = min(max((int)floorf(px), 0), GRID - 1);
    int cy = min(max((int)floorf(py), 0), GRID - 1);
    int cz = min(max((int)floorf(pz), 0), GRID - 1);
    float lx = px - (float)cx;
    float ly = py - (float)cy;
    float lz = pz - (float)cz;

    {
        const int EBX[12] = {0,1,0,0,0,1,0,0,0,1,1,0};
        const int EBY[12] = {0,0,1,0,0,0,1,0,0,0,1,1};
        const int EBZ[12] = {0,0,0,0,1,1,1,1,0,0,0,0};
        const int EAX[12] = {0,1,0,1,0,1,0,1,2,2,2,2};
#pragma unroll
        for (int e = 0; e < 12; e++) {
            int gx = cx + EBX[e];
            int gy = cy + EBY[e];
            int gz = cz + EBZ[e];
            t_s[tid * 13 + e] = offset[((EAX[e] * 33 + gx) * 33 + gy) * 33 + gz];
        }
    }
    // No barrier needed: each thread reads only its own LDS row.

    const float* trow = &t_s[tid * 13];
    float* outp = out + (((cx * GRID) + cy) * GRID + cz) * NT;

    for (int t = 0; t < NT; t++) {
        float dmin;
#pragma unroll
        for (int k = 0; k < 3; k++) {
            int ent = (t * 3 + k) * 3;
            // tri_table entries are wave-uniform (depend only on loop idx).
            int i0 = __builtin_amdgcn_readfirstlane(tri_table[ent + 0]);
            int i1 = __builtin_amdgcn_readfirstlane(tri_table[ent + 1]);
            int i2 = __builtin_amdgcn_readfirstlane(tri_table[ent + 2]);
            float t0 = trow[i0];
            float t1 = trow[i1];
            float t2 = trow[i2];
            float ax, ay, az, bx, by, bz, vcx, vcy, vcz;
            get_vert(i0, t0, ax, ay, az);
            get_vert(i1, t1, bx, by, bz);
            get_vert(i2, t2, vcx, vcy, vcz);
            float d = tri_dist_sq(lx, ly, lz, ax, ay, az, bx, by, bz, vcx, vcy, vcz);
            dmin = (k == 0) ? d : fminf(dmin, d);
        }
        atomicAdd(&outp[t], dmin);
    }
}

extern "C" void kernel_launch(void* const* d_in, const int* in_sizes, int n_in,
                              void* d_out, int out_size, void* d_ws, size_t ws_size,
                              hipStream_t stream) {
    const float* offset    = (const float*)d_in[0];
    const float* points    = (const float*)d_in[1];
    const int*   tri_table = (const int*)d_in[2];
    float* out = (float*)d_out;
    int n = in_sizes[1] / 3;  // 131072 points

    // Output is accumulated via atomics; harness poisons d_out with 0xAA.
    hipMemsetAsync(d_out, 0, (size_t)out_size * sizeof(float), stream);

    ptd_kernel<<<(n + BLK - 1) / BLK, BLK, 0, stream>>>(offset, points, tri_table, out, n);
}

// Round 2
// 326.128 us; speedup vs baseline: 1.2659x; 1.2659x over previous
//
#include <hip/hip_runtime.h>

#define GRID 32
#define NT 48
#define BLK 256
#define SPLIT 4              // threads per point; each handles NT/SPLIT=12 tris
#define PTS_PER_BLK (BLK / SPLIT)   // 64 points per block

// Per-edge packed info: bits [0]=base_x, [1]=base_y, [2]=base_z, [4:3]=axis.
// EDGE_BASE[e][axis[e]] == 0 for all 12 edges, so vert = base with comp[axis]=t.
#define EDGE_PACK ( (0ULL<<0) | (9ULL<<5) | (2ULL<<10) | (8ULL<<15) | \
                    (4ULL<<20) | (13ULL<<25) | (6ULL<<30) | (12ULL<<35) | \
                    (16ULL<<40) | (17ULL<<45) | (19ULL<<50) | (18ULL<<55) )

__device__ __forceinline__ float safe_div(float n, float d) {
    float dd = (fabsf(d) > 1e-12f) ? d : 1e-12f;
    return n / dd;
}

__device__ __forceinline__ void get_vert(int i, float t,
                                         float& vx, float& vy, float& vz) {
    unsigned nib = (unsigned)(EDGE_PACK >> (5 * i)) & 31u;
    float bx = (nib & 1u) ? 1.0f : 0.0f;
    float by = (nib & 2u) ? 1.0f : 0.0f;
    float bz = (nib & 4u) ? 1.0f : 0.0f;
    unsigned ax = nib >> 3;
    vx = (ax == 0u) ? t : bx;
    vy = (ax == 1u) ? t : by;
    vz = (ax == 2u) ? t : bz;
}

__device__ float tri_dist_sq(float px, float py, float pz,
                             float ax, float ay, float az,
                             float bx, float by, float bz,
                             float cx, float cy, float cz) {
#pragma clang fp contract(off)
    // Ericson closest-point-on-triangle, replicating the reference's exact
    // select ordering (later `where` wins) and safe_div eps semantics.
    float abx = bx - ax, aby = by - ay, abz = bz - az;
    float acx = cx - ax, acy = cy - ay, acz = cz - az;
    float apx = px - ax, apy = py - ay, apz = pz - az;
    float d1 = abx * apx + aby * apy + abz * apz;
    float d2 = acx * apx + acy * apy + acz * apz;
    float bpx = px - bx, bpy = py - by, bpz = pz - bz;
    float d3 = abx * bpx + aby * bpy + abz * bpz;
    float d4 = acx * bpx + acy * bpy + acz * bpz;
    float cpx = px - cx, cpy = py - cy, cpz = pz - cz;
    float d5 = abx * cpx + aby * cpy + abz * cpz;
    float d6 = acx * cpx + acy * cpy + acz * cpz;
    float vc = d1 * d4 - d3 * d2;
    float vb = d5 * d2 - d1 * d6;
    float va = d3 * d6 - d5 * d4;
    float v_ab = safe_div(d1, d1 - d3);
    float w_ac = safe_div(d2, d2 - d6);
    float w_bc = safe_div(d4 - d3, (d4 - d3) + (d5 - d6));
    float inv  = safe_div(1.0f, va + vb + vc);
    float v_in = vb * inv;
    float w_in = vc * inv;
    float qx = ax + abx * v_in + acx * w_in;
    float qy = ay + aby * v_in + acy * w_in;
    float qz = az + abz * v_in + acz * w_in;
    if ((va <= 0.0f) && (d4 - d3 >= 0.0f) && (d5 - d6 >= 0.0f)) {
        qx = bx + (cx - bx) * w_bc;
        qy = by + (cy - by) * w_bc;
        qz = bz + (cz - bz) * w_bc;
    }
    if ((vb <= 0.0f) && (d2 >= 0.0f) && (d6 <= 0.0f)) {
        qx = ax + acx * w_ac;
        qy = ay + acy * w_ac;
        qz = az + acz * w_ac;
    }
    if ((d6 >= 0.0f) && (d5 <= d6)) { qx = cx; qy = cy; qz = cz; }
    if ((vc <= 0.0f) && (d1 >= 0.0f) && (d3 <= 0.0f)) {
        qx = ax + abx * v_ab;
        qy = ay + aby * v_ab;
        qz = az + abz * v_ab;
    }
    if ((d3 >= 0.0f) && (d4 <= d3)) { qx = bx; qy = by; qz = bz; }
    if ((d1 <= 0.0f) && (d2 <= 0.0f)) { qx = ax; qy = ay; qz = az; }
    float dx = px - qx, dy = py - qy, dz = pz - qz;
    return dx * dx + dy * dy + dz * dz;
}

__global__ __launch_bounds__(BLK) void ptd_kernel(
    const float* __restrict__ offset,     // (3,33,33,33)
    const float* __restrict__ points,     // (N,3)
    const int*   __restrict__ tri_table,  // (48,3,3)
    float*       __restrict__ out,        // (32768,48)
    int n)
{
    // 13-float rows (stride 13: gcd(13,32)=1 -> no systematic conflicts);
    // one row per POINT now, shared by its SPLIT threads (broadcast reads).
    __shared__ float t_s[PTS_PER_BLK * 13];
    __shared__ int   t_tab[NT * 9];       // tri_table staged once per block

    const int tid = threadIdx.x;
    const int g   = blockIdx.x * BLK + tid;
    const int pt  = g >> 2;               // SPLIT=4
    const int grp = g & 3;
    const int pl  = tid >> 2;             // point-local row in this block
    const bool active = (pt < n);

    // Stage tri_table (432 ints) into LDS.
    for (int i = tid; i < NT * 9; i += BLK) t_tab[i] = tri_table[i];

    float px = 0.f, py = 0.f, pz = 0.f;
    int cx = 0, cy = 0, cz = 0;
    float lx = 0.f, ly = 0.f, lz = 0.f;
    if (active) {
        px = points[pt * 3 + 0];
        py = points[pt * 3 + 1];
        pz = points[pt * 3 + 2];
        cx = min(max((int)floorf(px), 0), GRID - 1);
        cy = min(max((int)floorf(py), 0), GRID - 1);
        cz = min(max((int)floorf(pz), 0), GRID - 1);
        lx = px - (float)cx;
        ly = py - (float)cy;
        lz = pz - (float)cz;
        // Cooperative edge gather: thread grp loads edges 3*grp .. 3*grp+2.
#pragma unroll
        for (int j = 0; j < 3; j++) {
            int e = grp * 3 + j;
            unsigned nib = (unsigned)(EDGE_PACK >> (5 * e)) & 31u;
            int gx = cx + (int)(nib & 1u);
            int gy = cy + (int)((nib >> 1) & 1u);
            int gz = cz + (int)((nib >> 2) & 1u);
            int ax = (int)(nib >> 3);
            t_s[pl * 13 + e] = offset[((ax * 33 + gx) * 33 + gy) * 33 + gz];
        }
    }
    __syncthreads();

    if (!active) return;

    const float* trow = &t_s[pl * 13];
    float* outp = out + ((((cx * GRID) + cy) * GRID + cz) * NT) + grp * (NT / SPLIT);

    for (int tt = 0; tt < NT / SPLIT; tt++) {
        const int t = grp * (NT / SPLIT) + tt;
        float dmin;
#pragma unroll
        for (int k = 0; k < 3; k++) {
            int ent = (t * 3 + k) * 3;
            int i0 = t_tab[ent + 0];
            int i1 = t_tab[ent + 1];
            int i2 = t_tab[ent + 2];
            float t0 = trow[i0];
            float t1 = trow[i1];
            float t2 = trow[i2];
            float ax, ay, az, bx, by, bz, vcx, vcy, vcz;
            get_vert(i0, t0, ax, ay, az);
            get_vert(i1, t1, bx, by, bz);
            get_vert(i2, t2, vcx, vcy, vcz);
            float d = tri_dist_sq(lx, ly, lz, ax, ay, az, bx, by, bz, vcx, vcy, vcz);
            dmin = (k == 0) ? d : fminf(dmin, d);
        }
        atomicAdd(&outp[tt], dmin);
    }
}

extern "C" void kernel_launch(void* const* d_in, const int* in_sizes, int n_in,
                              void* d_out, int out_size, void* d_ws, size_t ws_size,
                              hipStream_t stream) {
    const float* offset    = (const float*)d_in[0];
    const float* points    = (const float*)d_in[1];
    const int*   tri_table = (const int*)d_in[2];
    float* out = (float*)d_out;
    int n = in_sizes[1] / 3;  // 131072 points

    // Output is accumulated via atomics; harness poisons d_out with 0xAA.
    hipMemsetAsync(d_out, 0, (size_t)out_size * sizeof(float), stream);

    long total = (long)n * SPLIT;
    int blocks = (int)((total + BLK - 1) / BLK);
    ptd_kernel<<<blocks, BLK, 0, stream>>>(offset, points, tri_table, out, n);
}

// Round 3
// 134.499 us; speedup vs baseline: 3.0695x; 2.4248x over previous
//
#include <hip/hip_runtime.h>

#define GRID 32
#define NT 48
#define BLK 256
#define SPLIT 16                 // threads per point; each handles 3 t-rows = 9 tris
#define PPB (BLK / SPLIT)        // 16 points per block

// Per-edge packed info: bits [0]=base_x, [1]=base_y, [2]=base_z, [4:3]=axis.
// EDGE_BASE[e][axis[e]] == 0 for all 12 edges, so vert = base with comp[axis]=t.
#define EDGE_PACK ( (0ULL<<0) | (9ULL<<5) | (2ULL<<10) | (8ULL<<15) | \
                    (4ULL<<20) | (13ULL<<25) | (6ULL<<30) | (12ULL<<35) | \
                    (16ULL<<40) | (17ULL<<45) | (19ULL<<50) | (18ULL<<55) )

__device__ __forceinline__ float safe_div(float n, float d) {
    // Reference: n / (|d|>1e-12 ? d : 1e-12). v_rcp_f32 (~1ulp) is fine:
    // region-select conditions never depend on a division result, so the
    // only effect is a ~1e-7 relative perturbation of q.
    float dd = (fabsf(d) > 1e-12f) ? d : 1e-12f;
    return n * __builtin_amdgcn_rcpf(dd);
}

__device__ float tri_dist_sq(float px, float py, float pz,
                             float ax, float ay, float az,
                             float bx, float by, float bz,
                             float cx, float cy, float cz) {
#pragma clang fp contract(off)
    // Ericson closest-point-on-triangle, replicating the reference's exact
    // select ordering (later `where` wins) and safe_div eps semantics.
    float abx = bx - ax, aby = by - ay, abz = bz - az;
    float acx = cx - ax, acy = cy - ay, acz = cz - az;
    float apx = px - ax, apy = py - ay, apz = pz - az;
    float d1 = abx * apx + aby * apy + abz * apz;
    float d2 = acx * apx + acy * apy + acz * apz;
    float bpx = px - bx, bpy = py - by, bpz = pz - bz;
    float d3 = abx * bpx + aby * bpy + abz * bpz;
    float d4 = acx * bpx + acy * bpy + acz * bpz;
    float cpx = px - cx, cpy = py - cy, cpz = pz - cz;
    float d5 = abx * cpx + aby * cpy + abz * cpz;
    float d6 = acx * cpx + acy * cpy + acz * cpz;
    float vc = d1 * d4 - d3 * d2;
    float vb = d5 * d2 - d1 * d6;
    float va = d3 * d6 - d5 * d4;
    float v_ab = safe_div(d1, d1 - d3);
    float w_ac = safe_div(d2, d2 - d6);
    float w_bc = safe_div(d4 - d3, (d4 - d3) + (d5 - d6));
    float inv  = safe_div(1.0f, va + vb + vc);
    float v_in = vb * inv;
    float w_in = vc * inv;
    float qx = ax + abx * v_in + acx * w_in;
    float qy = ay + aby * v_in + acy * w_in;
    float qz = az + abz * v_in + acz * w_in;
    if ((va <= 0.0f) && (d4 - d3 >= 0.0f) && (d5 - d6 >= 0.0f)) {
        qx = bx + (cx - bx) * w_bc;
        qy = by + (cy - by) * w_bc;
        qz = bz + (cz - bz) * w_bc;
    }
    if ((vb <= 0.0f) && (d2 >= 0.0f) && (d6 <= 0.0f)) {
        qx = ax + acx * w_ac;
        qy = ay + acy * w_ac;
        qz = az + acz * w_ac;
    }
    if ((d6 >= 0.0f) && (d5 <= d6)) { qx = cx; qy = cy; qz = cz; }
    if ((vc <= 0.0f) && (d1 >= 0.0f) && (d3 <= 0.0f)) {
        qx = ax + abx * v_ab;
        qy = ay + aby * v_ab;
        qz = az + abz * v_ab;
    }
    if ((d3 >= 0.0f) && (d4 <= d3)) { qx = bx; qy = by; qz = bz; }
    if ((d1 <= 0.0f) && (d2 <= 0.0f)) { qx = ax; qy = ay; qz = az; }
    float dx = px - qx, dy = py - qy, dz = pz - qz;
    return dx * dx + dy * dy + dz * dz;
}

__global__ __launch_bounds__(BLK) void ptd_kernel(
    const float* __restrict__ offset,     // (3,33,33,33)
    const float* __restrict__ points,     // (N,3)
    const int*   __restrict__ tri_table,  // (48,3,3)
    float*       __restrict__ out,        // (32768,48)
    int n)
{
    // Precomputed edge VERTICES per point: 12 float4 (xyz + pad), row stride
    // 13 float4s -> row bank offsets {0,20,8,28}, worst-case free 2-way.
    __shared__ float4 v_s[PPB * 13];
    // tri_table packed: one int per (t,k): i0 | i1<<8 | i2<<16.
    __shared__ int t_tab[NT * 3];

    const int tid = threadIdx.x;
    const int g   = blockIdx.x * BLK + tid;
    const int pt  = g >> 4;               // SPLIT=16
    const int grp = tid & 15;
    const int pl  = tid >> 4;             // point-local row (0..15)
    const bool active = (pt < n);

    if (tid < NT * 3) {
        int i0 = tri_table[tid * 3 + 0];
        int i1 = tri_table[tid * 3 + 1];
        int i2 = tri_table[tid * 3 + 2];
        t_tab[tid] = i0 | (i1 << 8) | (i2 << 16);
    }

    int cx = 0, cy = 0, cz = 0;
    float lx = 0.f, ly = 0.f, lz = 0.f;
    if (active) {
        float px = points[pt * 3 + 0];
        float py = points[pt * 3 + 1];
        float pz = points[pt * 3 + 2];
        cx = min(max((int)floorf(px), 0), GRID - 1);
        cy = min(max((int)floorf(py), 0), GRID - 1);
        cz = min(max((int)floorf(pz), 0), GRID - 1);
        lx = px - (float)cx;
        ly = py - (float)cy;
        lz = pz - (float)cz;
        if (grp < 12) {
            // Thread grp gathers edge grp and stores its vertex.
            unsigned nib = (unsigned)(EDGE_PACK >> (5 * grp)) & 31u;
            int gx = cx + (int)(nib & 1u);
            int gy = cy + (int)((nib >> 1) & 1u);
            int gz = cz + (int)((nib >> 2) & 1u);
            int ax = (int)(nib >> 3);
            float t = offset[((ax * 33 + gx) * 33 + gy) * 33 + gz];
            float vx = (ax == 0) ? t : (float)(nib & 1u);
            float vy = (ax == 1) ? t : (float)((nib >> 1) & 1u);
            float vz = (ax == 2) ? t : (float)((nib >> 2) & 1u);
            v_s[pl * 13 + grp] = make_float4(vx, vy, vz, 0.0f);
        }
    }
    __syncthreads();

    if (!active) return;

    const float4* vrow = &v_s[pl * 13];
    float* outp = out + ((((cx * GRID) + cy) * GRID + cz) * NT);

#pragma unroll
    for (int r = 0; r < 3; r++) {
        const int t = grp * 3 + r;
        float dmin;
#pragma unroll
        for (int k = 0; k < 3; k++) {
            int packed = t_tab[t * 3 + k];
            float4 A = vrow[packed & 255];
            float4 B = vrow[(packed >> 8) & 255];
            float4 C = vrow[(packed >> 16) & 255];
            float d = tri_dist_sq(lx, ly, lz, A.x, A.y, A.z,
                                  B.x, B.y, B.z, C.x, C.y, C.z);
            dmin = (k == 0) ? d : fminf(dmin, d);
        }
        atomicAdd(&outp[t], dmin);
    }
}

extern "C" void kernel_launch(void* const* d_in, const int* in_sizes, int n_in,
                              void* d_out, int out_size, void* d_ws, size_t ws_size,
                              hipStream_t stream) {
    const float* offset    = (const float*)d_in[0];
    const float* points    = (const float*)d_in[1];
    const int*   tri_table = (const int*)d_in[2];
    float* out = (float*)d_out;
    int n = in_sizes[1] / 3;  // 131072 points

    // Output is accumulated via atomics; harness poisons d_out with 0xAA.
    hipMemsetAsync(d_out, 0, (size_t)out_size * sizeof(float), stream);

    long total = (long)n * SPLIT;
    int blocks = (int)((total + BLK - 1) / BLK);
    ptd_kernel<<<blocks, BLK, 0, stream>>>(offset, points, tri_table, out, n);
}

// Round 4
// 124.371 us; speedup vs baseline: 3.3195x; 1.0814x over previous
//
#include <hip/hip_runtime.h>

#define GRID 32
#define NT 48
#define BLK 256
#define SPLIT 16                 // threads per point; each handles 3 t-rows = 9 tris
#define PPB (BLK / SPLIT)        // 16 points per block

// Per-edge packed info: bits [0]=base_x, [1]=base_y, [2]=base_z, [4:3]=axis.
// EDGE_BASE[e][axis[e]] == 0 for all 12 edges, so vert = base with comp[axis]=t.
#define EDGE_PACK ( (0ULL<<0) | (9ULL<<5) | (2ULL<<10) | (8ULL<<15) | \
                    (4ULL<<20) | (13ULL<<25) | (6ULL<<30) | (12ULL<<35) | \
                    (16ULL<<40) | (17ULL<<45) | (19ULL<<50) | (18ULL<<55) )

__device__ __forceinline__ float safe_div(float n, float d) {
    // Reference: n / (|d|>1e-12 ? d : 1e-12). v_rcp_f32 (~1ulp): region
    // conditions never depend on a division result, so only q is perturbed.
    float dd = (fabsf(d) > 1e-12f) ? d : 1e-12f;
    return n * __builtin_amdgcn_rcpf(dd);
}

// Ericson closest-point-on-triangle, refactored on p-relative vectors:
// inputs are Ap=p-a, Bp=p-b, Cp=p-c. Then ab=b-a=Ap-Bp, ac=Ap-Cp, and the
// returned value is |p-q|^2 computed directly as |Ap - ab*v - ac*w|^2 per
// region (vertex regions degenerate to |Ap/Bp/Cp|^2). Select cascade order
// matches the reference exactly (later `where` wins). FMA contraction is
// allowed: flips only occur at region boundaries where q is continuous.
__device__ float tri_dist_sq(float Apx, float Apy, float Apz,
                             float Bpx, float Bpy, float Bpz,
                             float Cpx, float Cpy, float Cpz) {
    float abx = Apx - Bpx, aby = Apy - Bpy, abz = Apz - Bpz;
    float acx = Apx - Cpx, acy = Apy - Cpy, acz = Apz - Cpz;
    float d1 = abx * Apx + aby * Apy + abz * Apz;
    float d2 = acx * Apx + acy * Apy + acz * Apz;
    float d3 = abx * Bpx + aby * Bpy + abz * Bpz;
    float d4 = acx * Bpx + acy * Bpy + acz * Bpz;
    float d5 = abx * Cpx + aby * Cpy + abz * Cpz;
    float d6 = acx * Cpx + acy * Cpy + acz * Cpz;
    float vc = d1 * d4 - d3 * d2;
    float vb = d5 * d2 - d1 * d6;
    float va = d3 * d6 - d5 * d4;
    float d43 = d4 - d3;
    float d56 = d5 - d6;
    float v_ab = safe_div(d1, d1 - d3);
    float w_ac = safe_div(d2, d2 - d6);
    float w_bc = safe_div(d43, d43 + d56);
    float inv  = safe_div(1.0f, va + vb + vc);
    float v_in = vb * inv;
    float w_in = vc * inv;
    // interior
    float dx = Apx - abx * v_in - acx * w_in;
    float dy = Apy - aby * v_in - acy * w_in;
    float dz = Apz - abz * v_in - acz * w_in;
    // edge bc: q = b + (c-b)*w_bc, c-b = Bp-Cp
    if ((va <= 0.0f) && (d43 >= 0.0f) && (d56 >= 0.0f)) {
        dx = Bpx - (Bpx - Cpx) * w_bc;
        dy = Bpy - (Bpy - Cpy) * w_bc;
        dz = Bpz - (Bpz - Cpz) * w_bc;
    }
    // edge ac: q = a + ac*w_ac
    if ((vb <= 0.0f) && (d2 >= 0.0f) && (d6 <= 0.0f)) {
        dx = Apx - acx * w_ac;
        dy = Apy - acy * w_ac;
        dz = Apz - acz * w_ac;
    }
    // vertex c
    if ((d6 >= 0.0f) && (d5 <= d6)) { dx = Cpx; dy = Cpy; dz = Cpz; }
    // edge ab: q = a + ab*v_ab
    if ((vc <= 0.0f) && (d1 >= 0.0f) && (d3 <= 0.0f)) {
        dx = Apx - abx * v_ab;
        dy = Apy - aby * v_ab;
        dz = Apz - abz * v_ab;
    }
    // vertex b
    if ((d3 >= 0.0f) && (d4 <= d3)) { dx = Bpx; dy = Bpy; dz = Bpz; }
    // vertex a
    if ((d1 <= 0.0f) && (d2 <= 0.0f)) { dx = Apx; dy = Apy; dz = Apz; }
    return dx * dx + dy * dy + dz * dz;
}

__global__ __launch_bounds__(BLK) void ptd_kernel(
    const float* __restrict__ offset,     // (3,33,33,33)
    const float* __restrict__ points,     // (N,3)
    const int*   __restrict__ tri_table,  // (48,3,3)
    float*       __restrict__ out,        // (32768,48)
    int n)
{
    // Per-point rows of p-relative edge vertices: pv[e] = local - vert[e].
    // float4, row stride 13 -> row bank offsets {0,20,8,28}, free 2-way worst.
    __shared__ float4 v_s[PPB * 13];
    // tri_table packed: one int per (t,k): i0 | i1<<8 | i2<<16.
    __shared__ int t_tab[NT * 3];

    const int tid = threadIdx.x;
    const int g   = blockIdx.x * BLK + tid;
    const int pt  = g >> 4;               // SPLIT=16
    const int grp = tid & 15;
    const int pl  = tid >> 4;             // point-local row (0..15)
    const bool active = (pt < n);

    if (tid < NT * 3) {
        int i0 = tri_table[tid * 3 + 0];
        int i1 = tri_table[tid * 3 + 1];
        int i2 = tri_table[tid * 3 + 2];
        t_tab[tid] = i0 | (i1 << 8) | (i2 << 16);
    }

    int cx = 0, cy = 0, cz = 0;
    if (active) {
        float px = points[pt * 3 + 0];
        float py = points[pt * 3 + 1];
        float pz = points[pt * 3 + 2];
        cx = min(max((int)floorf(px), 0), GRID - 1);
        cy = min(max((int)floorf(py), 0), GRID - 1);
        cz = min(max((int)floorf(pz), 0), GRID - 1);
        if (grp < 12) {
            float lx = px - (float)cx;
            float ly = py - (float)cy;
            float lz = pz - (float)cz;
            // Thread grp gathers edge grp, stores local - vert.
            unsigned nib = (unsigned)(EDGE_PACK >> (5 * grp)) & 31u;
            int gx = cx + (int)(nib & 1u);
            int gy = cy + (int)((nib >> 1) & 1u);
            int gz = cz + (int)((nib >> 2) & 1u);
            int ax = (int)(nib >> 3);
            float t = offset[((ax * 33 + gx) * 33 + gy) * 33 + gz];
            float vx = (ax == 0) ? t : (float)(nib & 1u);
            float vy = (ax == 1) ? t : (float)((nib >> 1) & 1u);
            float vz = (ax == 2) ? t : (float)((nib >> 2) & 1u);
            v_s[pl * 13 + grp] = make_float4(lx - vx, ly - vy, lz - vz, 0.0f);
        }
    }
    __syncthreads();

    if (!active) return;

    const float4* vrow = &v_s[pl * 13];
    float* outp = out + ((((cx * GRID) + cy) * GRID + cz) * NT);

#pragma unroll
    for (int r = 0; r < 3; r++) {
        const int t = grp * 3 + r;
        float dmin;
#pragma unroll
        for (int k = 0; k < 3; k++) {
            int packed = t_tab[t * 3 + k];
            float4 A = vrow[packed & 255];
            float4 B = vrow[(packed >> 8) & 255];
            float4 C = vrow[(packed >> 16) & 255];
            float d = tri_dist_sq(A.x, A.y, A.z, B.x, B.y, B.z, C.x, C.y, C.z);
            dmin = (k == 0) ? d : fminf(dmin, d);
        }
        atomicAdd(&outp[t], dmin);
    }
}

extern "C" void kernel_launch(void* const* d_in, const int* in_sizes, int n_in,
                              void* d_out, int out_size, void* d_ws, size_t ws_size,
                              hipStream_t stream) {
    const float* offset    = (const float*)d_in[0];
    const float* points    = (const float*)d_in[1];
    const int*   tri_table = (const int*)d_in[2];
    float* out = (float*)d_out;
    int n = in_sizes[1] / 3;  // 131072 points

    // Output is accumulated via atomics; harness poisons d_out with 0xAA.
    hipMemsetAsync(d_out, 0, (size_t)out_size * sizeof(float), stream);

    long total = (long)n * SPLIT;
    int blocks = (int)((total + BLK - 1) / BLK);
    ptd_kernel<<<blocks, BLK, 0, stream>>>(offset, points, tri_table, out, n);
}